// Round 12
// baseline (116.827 us; speedup 1.0000x reference)
//
#include <hip/hip_runtime.h>
#include <hip/hip_bf16.h>

#define NN 8192
#define SD 512
#define HID 128
#define DE 128
#define KP1 11
#define EPSF 0.001f
#define NSPLIT 32
#define NCHUNK NSPLIT
#define PWAVE (2 * KP1 * 16)   // 352 floats per (wave,chunk) output

using short8 = __attribute__((ext_vector_type(8))) short;
using f32x4 = __attribute__((ext_vector_type(4))) float;

__device__ inline ushort f2bf(float f) {
    __hip_bfloat16 b = __float2bfloat16(f);
    return *reinterpret_cast<ushort*>(&b);
}
__device__ inline float bf2f(ushort u) {
    unsigned v = (unsigned)u << 16;
    union { unsigned u; float f; } c; c.u = v; return c.f;
}

// ---------------- Kernel 0: pre-split W1, W2 into hi/lo bf16
__global__ __launch_bounds__(256) void wsplit_kernel(
    const float* __restrict__ W1, const float* __restrict__ W2,
    ushort* __restrict__ W1h, ushort* __restrict__ W1l,
    ushort* __restrict__ W2h, ushort* __restrict__ W2l)
{
    const int bid = blockIdx.x;
    const float* src; ushort *dh, *dl; int base;
    if (bid < 64) { src = W1; dh = W1h; dl = W1l; base = bid * 1024; }
    else          { src = W2; dh = W2h; dl = W2l; base = (bid - 64) * 1024; }
    const int i = base + threadIdx.x * 4;
    float4 f = *reinterpret_cast<const float4*>(src + i);
    ushort h[4], lo[4];
    float fv[4] = {f.x, f.y, f.z, f.w};
#pragma unroll
    for (int j = 0; j < 4; ++j) {
        h[j] = f2bf(fv[j]);
        lo[j] = f2bf(fv[j] - bf2f(h[j]));
    }
    *reinterpret_cast<uint2*>(dh + i) = *reinterpret_cast<uint2*>(h);
    *reinterpret_cast<uint2*>(dl + i) = *reinterpret_cast<uint2*>(lo);
}

// ---------------- Kernel 1: split-bf16 MFMA MLP (unchanged except sqh output)
__global__ __launch_bounds__(256) void mlp_kernel(
    const float* __restrict__ s, const ushort* __restrict__ W1h,
    const ushort* __restrict__ W1l, const float* __restrict__ b1,
    const ushort* __restrict__ W2h, const ushort* __restrict__ W2l,
    const float* __restrict__ b2, __hip_bfloat16* __restrict__ xb,
    float* __restrict__ sqb, float* __restrict__ sqh)
{
    __shared__ __align__(16) ushort sbh[2][32 * 32];
    __shared__ __align__(16) ushort sbl[2][32 * 32];
    __shared__ __align__(16) ushort hbh[32 * 128];
    __shared__ __align__(16) ushort hbl[32 * 128];
    __shared__ __align__(16) ushort xtile[32 * 128];
    __shared__ float sqpart[4 * 32];

    const int t = threadIdx.x;
    const int w = t >> 6, l = t & 63;
    const int lc = l & 15, c4 = l >> 4;
    const int rb = blockIdx.x * 32;
    const int cb = w * 32;

    const int srow = t >> 3, skq = t & 7;
    const int ssl = ((skq >> 1) + (srow >> 2)) & 3;
    const int sByte = srow * 64 + (ssl ^ (srow & 3)) * 16 + (skq & 1) * 8;
    const float* sgbase = s + (size_t)(rb + srow) * SD + skq * 4;

    float4 sf;
#define STAGE_LOAD_S(kt_) sf = *reinterpret_cast<const float4*>(sgbase + (kt_) * 32)
#define STAGE_WRITE_S(b_) do { \
    float fv_[4] = {sf.x, sf.y, sf.z, sf.w}; \
    ushort h_[4], lo_[4]; \
    _Pragma("unroll") \
    for (int j_ = 0; j_ < 4; ++j_) { \
        h_[j_] = f2bf(fv_[j_]); \
        lo_[j_] = f2bf(fv_[j_] - bf2f(h_[j_])); \
    } \
    *reinterpret_cast<uint2*>(reinterpret_cast<char*>(sbh[b_]) + sByte) = *reinterpret_cast<uint2*>(h_); \
    *reinterpret_cast<uint2*>(reinterpret_cast<char*>(sbl[b_]) + sByte) = *reinterpret_cast<uint2*>(lo_); \
} while (0)

    int aByte[2];
#pragma unroll
    for (int rt = 0; rt < 2; ++rt) {
        int row = rt * 16 + lc;
        int sl = ((c4 + (row >> 2)) & 3) ^ (row & 3);
        aByte[rt] = row * 64 + sl * 16;
    }

    const ushort* w1hp[2]; const ushort* w1lp[2];
#pragma unroll
    for (int ct = 0; ct < 2; ++ct) {
        int col = cb + ct * 16 + lc;
        w1hp[ct] = W1h + (size_t)col * SD + c4 * 8;
        w1lp[ct] = W1l + (size_t)col * SD + c4 * 8;
    }

    f32x4 acc1[2][2];
#pragma unroll
    for (int rt = 0; rt < 2; ++rt)
#pragma unroll
        for (int ct = 0; ct < 2; ++ct) acc1[rt][ct] = {0.f, 0.f, 0.f, 0.f};

    STAGE_LOAD_S(0);
    STAGE_WRITE_S(0);
    short8 bh[2], bl[2], nbh[2], nbl[2];
#pragma unroll
    for (int ct = 0; ct < 2; ++ct) {
        bh[ct] = *reinterpret_cast<const short8*>(w1hp[ct]);
        bl[ct] = *reinterpret_cast<const short8*>(w1lp[ct]);
    }

    for (int kt = 0; kt < 16; ++kt) {
        __syncthreads();
        if (kt < 15) STAGE_LOAD_S(kt + 1);
        short8 ah[2], al[2];
#pragma unroll
        for (int rt = 0; rt < 2; ++rt) {
            ah[rt] = *reinterpret_cast<const short8*>(
                reinterpret_cast<char*>(sbh[kt & 1]) + aByte[rt]);
            al[rt] = *reinterpret_cast<const short8*>(
                reinterpret_cast<char*>(sbl[kt & 1]) + aByte[rt]);
        }
        if (kt < 15) {
#pragma unroll
            for (int ct = 0; ct < 2; ++ct) {
                nbh[ct] = *reinterpret_cast<const short8*>(w1hp[ct] + (kt + 1) * 32);
                nbl[ct] = *reinterpret_cast<const short8*>(w1lp[ct] + (kt + 1) * 32);
            }
        }
#pragma unroll
        for (int rt = 0; rt < 2; ++rt)
#pragma unroll
            for (int ct = 0; ct < 2; ++ct) {
                acc1[rt][ct] = __builtin_amdgcn_mfma_f32_16x16x32_bf16(ah[rt], bh[ct], acc1[rt][ct], 0, 0, 0);
                acc1[rt][ct] = __builtin_amdgcn_mfma_f32_16x16x32_bf16(ah[rt], bl[ct], acc1[rt][ct], 0, 0, 0);
                acc1[rt][ct] = __builtin_amdgcn_mfma_f32_16x16x32_bf16(al[rt], bh[ct], acc1[rt][ct], 0, 0, 0);
            }
        if (kt < 15) {
            STAGE_WRITE_S((kt + 1) & 1);
#pragma unroll
            for (int ct = 0; ct < 2; ++ct) { bh[ct] = nbh[ct]; bl[ct] = nbl[ct]; }
        }
    }

    float b1v[2];
#pragma unroll
    for (int ct = 0; ct < 2; ++ct) b1v[ct] = b1[cb + ct * 16 + lc];
#pragma unroll
    for (int rt = 0; rt < 2; ++rt)
#pragma unroll
        for (int ct = 0; ct < 2; ++ct)
#pragma unroll
            for (int reg = 0; reg < 4; ++reg) {
                float v = fmaxf(acc1[rt][ct][reg] + b1v[ct], 0.f);
                ushort hh = f2bf(v);
                ushort hl = f2bf(v - bf2f(hh));
                int row = rt * 16 + c4 * 4 + reg;
                int kcol = cb + ct * 16 + lc;
                int sl = (kcol >> 3) ^ (row & 15);
                int byte = row * 256 + sl * 16 + (kcol & 7) * 2;
                *reinterpret_cast<ushort*>(reinterpret_cast<char*>(hbh) + byte) = hh;
                *reinterpret_cast<ushort*>(reinterpret_cast<char*>(hbl) + byte) = hl;
            }
    __syncthreads();

    f32x4 acc2[2][2];
#pragma unroll
    for (int rt = 0; rt < 2; ++rt)
#pragma unroll
        for (int ct = 0; ct < 2; ++ct) acc2[rt][ct] = {0.f, 0.f, 0.f, 0.f};

#pragma unroll
    for (int kt = 0; kt < 4; ++kt) {
        short8 ah[2], al[2];
#pragma unroll
        for (int rt = 0; rt < 2; ++rt) {
            int row = rt * 16 + lc;
            int sl = (kt * 4 + c4) ^ (row & 15);
            int byte = row * 256 + sl * 16;
            ah[rt] = *reinterpret_cast<const short8*>(reinterpret_cast<char*>(hbh) + byte);
            al[rt] = *reinterpret_cast<const short8*>(reinterpret_cast<char*>(hbl) + byte);
        }
        short8 wh[2], wl[2];
#pragma unroll
        for (int ct = 0; ct < 2; ++ct) {
            int col = cb + ct * 16 + lc;
            wh[ct] = *reinterpret_cast<const short8*>(W2h + (size_t)col * HID + kt * 32 + c4 * 8);
            wl[ct] = *reinterpret_cast<const short8*>(W2l + (size_t)col * HID + kt * 32 + c4 * 8);
        }
#pragma unroll
        for (int rt = 0; rt < 2; ++rt)
#pragma unroll
            for (int ct = 0; ct < 2; ++ct) {
                acc2[rt][ct] = __builtin_amdgcn_mfma_f32_16x16x32_bf16(ah[rt], wh[ct], acc2[rt][ct], 0, 0, 0);
                acc2[rt][ct] = __builtin_amdgcn_mfma_f32_16x16x32_bf16(ah[rt], wl[ct], acc2[rt][ct], 0, 0, 0);
                acc2[rt][ct] = __builtin_amdgcn_mfma_f32_16x16x32_bf16(al[rt], wh[ct], acc2[rt][ct], 0, 0, 0);
            }
    }

    float b2v[2];
#pragma unroll
    for (int ct = 0; ct < 2; ++ct) b2v[ct] = b2[cb + ct * 16 + lc];
    float p[8];
#pragma unroll
    for (int j = 0; j < 8; ++j) p[j] = 0.f;
#pragma unroll
    for (int rt = 0; rt < 2; ++rt)
#pragma unroll
        for (int ct = 0; ct < 2; ++ct)
#pragma unroll
            for (int reg = 0; reg < 4; ++reg) {
                float v = acc2[rt][ct][reg] + b2v[ct];
                ushort xv = f2bf(v);
                float xf = bf2f(xv);
                p[rt * 4 + reg] = fmaf(xf, xf, p[rt * 4 + reg]);
                int row = rt * 16 + c4 * 4 + reg;
                int e = cb + ct * 16 + lc;
                xtile[row * 128 + e] = xv;
            }
#pragma unroll
    for (int j = 0; j < 8; ++j) {
#pragma unroll
        for (int off = 8; off >= 1; off >>= 1) p[j] += __shfl_xor(p[j], off, 16);
    }
    if (lc == 0) {
#pragma unroll
        for (int rt = 0; rt < 2; ++rt)
#pragma unroll
            for (int reg = 0; reg < 4; ++reg)
                sqpart[w * 32 + rt * 16 + c4 * 4 + reg] = p[rt * 4 + reg];
    }
    __syncthreads();
    if (t < 32) {
        float sq = sqpart[t] + sqpart[32 + t] + sqpart[64 + t] + sqpart[96 + t];
        sqb[rb + t] = sq;
        sqh[rb + t] = 0.5f * sq;
    }
    const short8* xsv = reinterpret_cast<const short8*>(xtile);
    short8* xg = reinterpret_cast<short8*>(reinterpret_cast<ushort*>(xb) + (size_t)rb * DE);
    xg[t] = xsv[t];
    xg[t + 256] = xsv[t + 256];
}

// ---------------- Kernel 2: per-row top-11 of d2'' = sq[c]/2 - x_q.x_c.
// BARRIER-FREE: no LDS, 4-wave blocks, each wave independent. A-frags + sqh read
// straight from global (L2-resident 2MB xs). Register ping-pong one-subtile
// prefetch. lg-partial lists merged in-wave via shfl_xor butterfly.
__global__ __launch_bounds__(256) void knn_kernel(
    const ushort* __restrict__ xs, const float* __restrict__ sqh,
    float* __restrict__ part)
{
    const int bid = blockIdx.x;              // 2048 = 64 rid x 32 cid
    const int rid = bid >> 5, cid = bid & 31;
    const int t = threadIdx.x;
    const int w = t >> 6, l = t & 63;
    const int q16 = l & 15, lg = l >> 4;
    const int kk = lg * 8;
    const int qb = rid * 128 + w * 32;
    const int cstart = cid * (NN / NSPLIT);  // 256 candidates per block

    // B-frags: NEGATED queries (sign-bit XOR on packed bf16 pairs; exact)
    short8 bq[2][4];
#pragma unroll
    for (int qs = 0; qs < 2; ++qs)
#pragma unroll
        for (int kb = 0; kb < 4; ++kb) {
            bq[qs][kb] = *reinterpret_cast<const short8*>(
                xs + (size_t)(qb + qs * 16 + q16) * DE + kb * 32 + kk);
            unsigned* u = reinterpret_cast<unsigned*>(&bq[qs][kb]);
#pragma unroll
            for (int i = 0; i < 4; ++i) u[i] ^= 0x80008000u;
        }

    float m[2][KP1];
#pragma unroll
    for (int qs = 0; qs < 2; ++qs)
#pragma unroll
        for (int j = 0; j < KP1; ++j) m[qs][j] = 1e30f;

#define INS(qs_, v_) do { \
    float d2_ = (v_); \
    _Pragma("unroll") \
    for (int j_ = KP1 - 1; j_ >= 1; --j_) \
        m[qs_][j_] = __builtin_amdgcn_fmed3f(d2_, m[qs_][j_ - 1], m[qs_][j_]); \
    m[qs_][0] = fminf(d2_, m[qs_][0]); \
} while (0)

    // per-lane candidate fragment base: cand row = c0 + q16, elems kk..kk+7
    const ushort* abase = xs + (size_t)(cstart + q16) * DE + kk;
    const float*  sbase = sqh + cstart + lg * 4;

    short8 aA[4], aB[4];
    float4 svA, svB;
#define LOADT(A, S, st_) do { \
    const ushort* p_ = abase + (size_t)(st_) * 16 * DE; \
    (A)[0] = *reinterpret_cast<const short8*>(p_); \
    (A)[1] = *reinterpret_cast<const short8*>(p_ + 32); \
    (A)[2] = *reinterpret_cast<const short8*>(p_ + 64); \
    (A)[3] = *reinterpret_cast<const short8*>(p_ + 96); \
    (S) = *reinterpret_cast<const float4*>(sbase + (st_) * 16); \
} while (0)
#define PROC(A, S) do { \
    _Pragma("unroll") \
    for (int qs_ = 0; qs_ < 2; ++qs_) { \
        f32x4 acc_ = {(S).x, (S).y, (S).z, (S).w}; \
        _Pragma("unroll") \
        for (int kb_ = 0; kb_ < 4; ++kb_) \
            acc_ = __builtin_amdgcn_mfma_f32_16x16x32_bf16((A)[kb_], bq[qs_][kb_], acc_, 0, 0, 0); \
        INS(qs_, acc_[0]); \
        INS(qs_, acc_[1]); \
        INS(qs_, acc_[2]); \
        INS(qs_, acc_[3]); \
    } \
} while (0)

    LOADT(aA, svA, 0);
    for (int st = 0; st < 16; st += 2) {     // 16 subtiles of 16 candidates
        if (st + 1 < 16) LOADT(aB, svB, st + 1);
        PROC(aA, svA);
        if (st + 2 < 16) LOADT(aA, svA, st + 2);
        PROC(aB, svB);
    }
#undef LOADT
#undef PROC

    // ---- in-wave butterfly merge of the 4 lg-partial lists (no LDS, no barrier)
#pragma unroll
    for (int stage = 16; stage <= 32; stage <<= 1) {
#pragma unroll
        for (int qs = 0; qs < 2; ++qs) {
            float other[KP1];
#pragma unroll
            for (int j = 0; j < KP1; ++j)
                other[j] = __shfl_xor(m[qs][j], stage, 64);
#pragma unroll
            for (int j = 0; j < KP1; ++j)
                INS(qs, other[j]);
        }
    }
#undef INS

    // lanes 0..15 hold the final merged lists; block-contiguous write
    if (lg == 0) {
        float* pout = part + (size_t)((rid * 4 + w) * NSPLIT + cid) * PWAVE;
#pragma unroll
        for (int qs = 0; qs < 2; ++qs)
#pragma unroll
            for (int j = 0; j < KP1; ++j)
                pout[qs * (KP1 * 16) + j * 16 + q16] = m[qs][j];
    }
}

// ---------------- Kernel 3: merge 32 partial lists -> sumk; block partial sums.
// dist^2 = 2*m + sqq (m holds sq[c]/2 - dot).
__global__ __launch_bounds__(256) void merge_kernel(
    const float* __restrict__ part, const float* __restrict__ sqb,
    float* __restrict__ sumk, float* __restrict__ psum)
{
    const int row = blockIdx.x * 256 + threadIdx.x;
    const int qgroup = row >> 5;             // which knn wave (32 queries each)
    const int qs = (row >> 4) & 1;
    const int lane = row & 15;
    const float* pbase = part + (size_t)qgroup * NSPLIT * PWAVE + qs * (KP1 * 16) + lane;

    float m[KP1];
#pragma unroll
    for (int j = 0; j < KP1; ++j) m[j] = 1e30f;
#pragma unroll 4
    for (int ch = 0; ch < NCHUNK; ++ch) {
        const float* pc = pbase + ch * PWAVE;
#pragma unroll
        for (int j = 0; j < KP1; ++j) {
            float d2 = pc[j * 16];
#pragma unroll
            for (int jj = KP1 - 1; jj >= 1; --jj)
                m[jj] = __builtin_amdgcn_fmed3f(d2, m[jj - 1], m[jj]);
            m[0] = fminf(d2, m[0]);
        }
    }
    const float sqq = sqb[row];
    float sum = 0.f;
#pragma unroll
    for (int j = 1; j < KP1; ++j)
        sum += sqrtf(fmaxf(fmaf(2.f, m[j], sqq), 1e-12f));
    sumk[row] = sum;

    float p = sum;
#pragma unroll
    for (int off = 32; off >= 1; off >>= 1) p += __shfl_xor(p, off, 64);
    __shared__ float red[4];
    if ((threadIdx.x & 63) == 0) red[threadIdx.x >> 6] = p;
    __syncthreads();
    if (threadIdx.x == 0) psum[blockIdx.x] = red[0] + red[1] + red[2] + red[3];
}

// ---------------- Kernel 4: mean over 32 partials -> q = EPS * mean^2
__global__ void reduce_kernel(const float* __restrict__ psum, float* __restrict__ qv)
{
    const int t = threadIdx.x;
    float p = (t < 32) ? psum[t] : 0.f;
#pragma unroll
    for (int off = 32; off >= 1; off >>= 1) p += __shfl_xor(p, off, 64);
    if (t == 0) {
        float mean = p * (1.0f / NN);
        qv[0] = EPSF * mean * mean;
    }
}

// ---------------- Kernel 5: out = q / (s^2 + q)
__global__ __launch_bounds__(256) void final_kernel(
    const float* __restrict__ sumk, const float* __restrict__ qv,
    float* __restrict__ out)
{
    const int i = blockIdx.x * 256 + threadIdx.x;
    const float qq = qv[0];
    const float sv = sumk[i];
    out[i] = qq / (fmaf(sv, sv, qq));
}

extern "C" void kernel_launch(void* const* d_in, const int* in_sizes, int n_in,
                              void* d_out, int out_size, void* d_ws, size_t ws_size,
                              hipStream_t stream)
{
    const float* s  = (const float*)d_in[0];
    const float* W1 = (const float*)d_in[1];
    const float* b1 = (const float*)d_in[2];
    const float* W2 = (const float*)d_in[3];
    const float* b2 = (const float*)d_in[4];
    float* out = (float*)d_out;

    char* ws = (char*)d_ws;
    __hip_bfloat16* xb = (__hip_bfloat16*)ws;                       // 2 MB
    float* sqb  = (float*)(ws + (size_t)NN * DE * 2);               // 32 KB
    float* sqh  = sqb + NN;                                         // 32 KB
    float* part = sqh + NN;                                         // 256*32*352*4 = 11.5 MB
    float* sumk = part + (size_t)256 * NSPLIT * PWAVE;              // 32 KB
    float* psum = sumk + NN;                                        // 128 B
    float* qv   = psum + 32;                                        // 4 B
    ushort* W1h = (ushort*)(qv + 1);                                // 128 KB
    ushort* W1l = W1h + (size_t)HID * SD;                           // 128 KB
    ushort* W2h = W1l + (size_t)HID * SD;                           // 32 KB
    ushort* W2l = W2h + (size_t)DE * HID;                           // 32 KB

    wsplit_kernel<<<80, 256, 0, stream>>>(W1, W2, W1h, W1l, W2h, W2l);
    mlp_kernel<<<NN / 32, 256, 0, stream>>>(s, W1h, W1l, b1, W2h, W2l, b2, xb, sqb, sqh);
    knn_kernel<<<(NN / 128) * NSPLIT, 256, 0, stream>>>((const ushort*)xb, sqh, part);
    merge_kernel<<<NN / 256, 256, 0, stream>>>(part, sqb, sumk, psum);
    reduce_kernel<<<1, 64, 0, stream>>>(psum, qv);
    final_kernel<<<NN / 256, 256, 0, stream>>>(sumk, qv, out);
}

// Round 13
// 80.568 us; speedup vs baseline: 1.4500x; 1.4500x over previous
//
#include <hip/hip_runtime.h>
#include <hip/hip_bf16.h>

#define NN 8192
#define SD 512
#define HID 128
#define DE 128
#define KP1 11
#define EPSF 0.001f
#define NSPLIT 16
#define NCHUNK NSPLIT
#define TILE 64
#define NTILE ((NN / NSPLIT) / TILE)   // 8 tiles of 64 candidates per block
#define PBLK (4 * 2 * KP1 * 16)        // 1408 floats = 5632 B per block, contiguous

using short8 = __attribute__((ext_vector_type(8))) short;
using f32x4 = __attribute__((ext_vector_type(4))) float;

__device__ inline ushort f2bf(float f) {
    __hip_bfloat16 b = __float2bfloat16(f);
    return *reinterpret_cast<ushort*>(&b);
}
__device__ inline float bf2f(ushort u) {
    unsigned v = (unsigned)u << 16;
    union { unsigned u; float f; } c; c.u = v; return c.f;
}

// ---------------- Kernel 0: pre-split W1, W2 into hi/lo bf16
__global__ __launch_bounds__(256) void wsplit_kernel(
    const float* __restrict__ W1, const float* __restrict__ W2,
    ushort* __restrict__ W1h, ushort* __restrict__ W1l,
    ushort* __restrict__ W2h, ushort* __restrict__ W2l)
{
    const int bid = blockIdx.x;
    const float* src; ushort *dh, *dl; int base;
    if (bid < 64) { src = W1; dh = W1h; dl = W1l; base = bid * 1024; }
    else          { src = W2; dh = W2h; dl = W2l; base = (bid - 64) * 1024; }
    const int i = base + threadIdx.x * 4;
    float4 f = *reinterpret_cast<const float4*>(src + i);
    ushort h[4], lo[4];
    float fv[4] = {f.x, f.y, f.z, f.w};
#pragma unroll
    for (int j = 0; j < 4; ++j) {
        h[j] = f2bf(fv[j]);
        lo[j] = f2bf(fv[j] - bf2f(h[j]));
    }
    *reinterpret_cast<uint2*>(dh + i) = *reinterpret_cast<uint2*>(h);
    *reinterpret_cast<uint2*>(dl + i) = *reinterpret_cast<uint2*>(lo);
}

// ---------------- Kernel 1: split-bf16 MFMA MLP. Block = 32 rows x 128 cols, 4 waves.
__global__ __launch_bounds__(256) void mlp_kernel(
    const float* __restrict__ s, const ushort* __restrict__ W1h,
    const ushort* __restrict__ W1l, const float* __restrict__ b1,
    const ushort* __restrict__ W2h, const ushort* __restrict__ W2l,
    const float* __restrict__ b2, __hip_bfloat16* __restrict__ xb,
    float* __restrict__ sqb)
{
    __shared__ __align__(16) ushort sbh[2][32 * 32];
    __shared__ __align__(16) ushort sbl[2][32 * 32];
    __shared__ __align__(16) ushort hbh[32 * 128];
    __shared__ __align__(16) ushort hbl[32 * 128];
    __shared__ __align__(16) ushort xtile[32 * 128];
    __shared__ float sqpart[4 * 32];

    const int t = threadIdx.x;
    const int w = t >> 6, l = t & 63;
    const int lc = l & 15, c4 = l >> 4;
    const int rb = blockIdx.x * 32;
    const int cb = w * 32;

    const int srow = t >> 3, skq = t & 7;
    const int ssl = ((skq >> 1) + (srow >> 2)) & 3;
    const int sByte = srow * 64 + (ssl ^ (srow & 3)) * 16 + (skq & 1) * 8;
    const float* sgbase = s + (size_t)(rb + srow) * SD + skq * 4;

    float4 sf;
#define STAGE_LOAD_S(kt_) sf = *reinterpret_cast<const float4*>(sgbase + (kt_) * 32)
#define STAGE_WRITE_S(b_) do { \
    float fv_[4] = {sf.x, sf.y, sf.z, sf.w}; \
    ushort h_[4], lo_[4]; \
    _Pragma("unroll") \
    for (int j_ = 0; j_ < 4; ++j_) { \
        h_[j_] = f2bf(fv_[j_]); \
        lo_[j_] = f2bf(fv_[j_] - bf2f(h_[j_])); \
    } \
    *reinterpret_cast<uint2*>(reinterpret_cast<char*>(sbh[b_]) + sByte) = *reinterpret_cast<uint2*>(h_); \
    *reinterpret_cast<uint2*>(reinterpret_cast<char*>(sbl[b_]) + sByte) = *reinterpret_cast<uint2*>(lo_); \
} while (0)

    int aByte[2];
#pragma unroll
    for (int rt = 0; rt < 2; ++rt) {
        int row = rt * 16 + lc;
        int sl = ((c4 + (row >> 2)) & 3) ^ (row & 3);
        aByte[rt] = row * 64 + sl * 16;
    }

    const ushort* w1hp[2]; const ushort* w1lp[2];
#pragma unroll
    for (int ct = 0; ct < 2; ++ct) {
        int col = cb + ct * 16 + lc;
        w1hp[ct] = W1h + (size_t)col * SD + c4 * 8;
        w1lp[ct] = W1l + (size_t)col * SD + c4 * 8;
    }

    f32x4 acc1[2][2];
#pragma unroll
    for (int rt = 0; rt < 2; ++rt)
#pragma unroll
        for (int ct = 0; ct < 2; ++ct) acc1[rt][ct] = {0.f, 0.f, 0.f, 0.f};

    STAGE_LOAD_S(0);
    STAGE_WRITE_S(0);
    short8 bh[2], bl[2], nbh[2], nbl[2];
#pragma unroll
    for (int ct = 0; ct < 2; ++ct) {
        bh[ct] = *reinterpret_cast<const short8*>(w1hp[ct]);
        bl[ct] = *reinterpret_cast<const short8*>(w1lp[ct]);
    }

    for (int kt = 0; kt < 16; ++kt) {
        __syncthreads();
        if (kt < 15) STAGE_LOAD_S(kt + 1);
        short8 ah[2], al[2];
#pragma unroll
        for (int rt = 0; rt < 2; ++rt) {
            ah[rt] = *reinterpret_cast<const short8*>(
                reinterpret_cast<char*>(sbh[kt & 1]) + aByte[rt]);
            al[rt] = *reinterpret_cast<const short8*>(
                reinterpret_cast<char*>(sbl[kt & 1]) + aByte[rt]);
        }
        if (kt < 15) {
#pragma unroll
            for (int ct = 0; ct < 2; ++ct) {
                nbh[ct] = *reinterpret_cast<const short8*>(w1hp[ct] + (kt + 1) * 32);
                nbl[ct] = *reinterpret_cast<const short8*>(w1lp[ct] + (kt + 1) * 32);
            }
        }
#pragma unroll
        for (int rt = 0; rt < 2; ++rt)
#pragma unroll
            for (int ct = 0; ct < 2; ++ct) {
                acc1[rt][ct] = __builtin_amdgcn_mfma_f32_16x16x32_bf16(ah[rt], bh[ct], acc1[rt][ct], 0, 0, 0);
                acc1[rt][ct] = __builtin_amdgcn_mfma_f32_16x16x32_bf16(ah[rt], bl[ct], acc1[rt][ct], 0, 0, 0);
                acc1[rt][ct] = __builtin_amdgcn_mfma_f32_16x16x32_bf16(al[rt], bh[ct], acc1[rt][ct], 0, 0, 0);
            }
        if (kt < 15) {
            STAGE_WRITE_S((kt + 1) & 1);
#pragma unroll
            for (int ct = 0; ct < 2; ++ct) { bh[ct] = nbh[ct]; bl[ct] = nbl[ct]; }
        }
    }

    float b1v[2];
#pragma unroll
    for (int ct = 0; ct < 2; ++ct) b1v[ct] = b1[cb + ct * 16 + lc];
#pragma unroll
    for (int rt = 0; rt < 2; ++rt)
#pragma unroll
        for (int ct = 0; ct < 2; ++ct)
#pragma unroll
            for (int reg = 0; reg < 4; ++reg) {
                float v = fmaxf(acc1[rt][ct][reg] + b1v[ct], 0.f);
                ushort hh = f2bf(v);
                ushort hl = f2bf(v - bf2f(hh));
                int row = rt * 16 + c4 * 4 + reg;
                int kcol = cb + ct * 16 + lc;
                int sl = (kcol >> 3) ^ (row & 15);
                int byte = row * 256 + sl * 16 + (kcol & 7) * 2;
                *reinterpret_cast<ushort*>(reinterpret_cast<char*>(hbh) + byte) = hh;
                *reinterpret_cast<ushort*>(reinterpret_cast<char*>(hbl) + byte) = hl;
            }
    __syncthreads();

    f32x4 acc2[2][2];
#pragma unroll
    for (int rt = 0; rt < 2; ++rt)
#pragma unroll
        for (int ct = 0; ct < 2; ++ct) acc2[rt][ct] = {0.f, 0.f, 0.f, 0.f};

#pragma unroll
    for (int kt = 0; kt < 4; ++kt) {
        short8 ah[2], al[2];
#pragma unroll
        for (int rt = 0; rt < 2; ++rt) {
            int row = rt * 16 + lc;
            int sl = (kt * 4 + c4) ^ (row & 15);
            int byte = row * 256 + sl * 16;
            ah[rt] = *reinterpret_cast<const short8*>(reinterpret_cast<char*>(hbh) + byte);
            al[rt] = *reinterpret_cast<const short8*>(reinterpret_cast<char*>(hbl) + byte);
        }
        short8 wh[2], wl[2];
#pragma unroll
        for (int ct = 0; ct < 2; ++ct) {
            int col = cb + ct * 16 + lc;
            wh[ct] = *reinterpret_cast<const short8*>(W2h + (size_t)col * HID + kt * 32 + c4 * 8);
            wl[ct] = *reinterpret_cast<const short8*>(W2l + (size_t)col * HID + kt * 32 + c4 * 8);
        }
#pragma unroll
        for (int rt = 0; rt < 2; ++rt)
#pragma unroll
            for (int ct = 0; ct < 2; ++ct) {
                acc2[rt][ct] = __builtin_amdgcn_mfma_f32_16x16x32_bf16(ah[rt], wh[ct], acc2[rt][ct], 0, 0, 0);
                acc2[rt][ct] = __builtin_amdgcn_mfma_f32_16x16x32_bf16(ah[rt], wl[ct], acc2[rt][ct], 0, 0, 0);
                acc2[rt][ct] = __builtin_amdgcn_mfma_f32_16x16x32_bf16(al[rt], wh[ct], acc2[rt][ct], 0, 0, 0);
            }
    }

    float b2v[2];
#pragma unroll
    for (int ct = 0; ct < 2; ++ct) b2v[ct] = b2[cb + ct * 16 + lc];
    float p[8];
#pragma unroll
    for (int j = 0; j < 8; ++j) p[j] = 0.f;
#pragma unroll
    for (int rt = 0; rt < 2; ++rt)
#pragma unroll
        for (int ct = 0; ct < 2; ++ct)
#pragma unroll
            for (int reg = 0; reg < 4; ++reg) {
                float v = acc2[rt][ct][reg] + b2v[ct];
                ushort xv = f2bf(v);
                float xf = bf2f(xv);
                p[rt * 4 + reg] = fmaf(xf, xf, p[rt * 4 + reg]);
                int row = rt * 16 + c4 * 4 + reg;
                int e = cb + ct * 16 + lc;
                xtile[row * 128 + e] = xv;
            }
#pragma unroll
    for (int j = 0; j < 8; ++j) {
#pragma unroll
        for (int off = 8; off >= 1; off >>= 1) p[j] += __shfl_xor(p[j], off, 16);
    }
    if (lc == 0) {
#pragma unroll
        for (int rt = 0; rt < 2; ++rt)
#pragma unroll
            for (int reg = 0; reg < 4; ++reg)
                sqpart[w * 32 + rt * 16 + c4 * 4 + reg] = p[rt * 4 + reg];
    }
    __syncthreads();
    if (t < 32)
        sqb[rb + t] = sqpart[t] + sqpart[32 + t] + sqpart[64 + t] + sqpart[96 + t];
    const short8* xsv = reinterpret_cast<const short8*>(xtile);
    short8* xg = reinterpret_cast<short8*>(reinterpret_cast<ushort*>(xb) + (size_t)rb * DE);
    xg[t] = xsv[t];
    xg[t + 256] = xsv[t + 256];
}

// ---------------- Kernel 2: per-row top-11 of d2'' = sq[c]/2 - x_q.x_c.
// r5 geometry (best measured): 4-wave blocks, NSPLIT=16, TILE=64, LDS dbuf.
// NEW: ILP-batched inner loop — all 32 MFMAs of a 64-cand tile issued as 8
// independent chains into acc[4][2] BEFORE the 352 insert ops, so MFMA latency
// hides under the previous subtiles' inserts within a single wave.
__global__ __launch_bounds__(256) void knn_kernel(
    const ushort* __restrict__ xs, const float* __restrict__ sqb,
    float* __restrict__ part)
{
    __shared__ __align__(16) ushort lbuf[2][TILE * DE];   // 2 x 16KB (merge overlays)
    __shared__ __align__(16) float sqs[NN / NSPLIT];      // 2KB

    const int bid = blockIdx.x;              // 1024 = 64 row-groups x 16 cand-splits
    const int rid = bid >> 4, cid = bid & 15;
    const int t = threadIdx.x;
    const int w = t >> 6, l = t & 63;
    const int q16 = l & 15, lg = l >> 4;
    const int kk = lg * 8;
    const int qb = rid * 128 + w * 32;
    const int cstart = cid * (NN / NSPLIT);  // 512 candidates per block

    // B-frags: NEGATED queries (sign-bit XOR on packed bf16 pairs; exact)
    short8 bq[2][4];
#pragma unroll
    for (int qs = 0; qs < 2; ++qs)
#pragma unroll
        for (int kb = 0; kb < 4; ++kb) {
            bq[qs][kb] = *reinterpret_cast<const short8*>(
                xs + (size_t)(qb + qs * 16 + q16) * DE + kb * 32 + kk);
            unsigned* u = reinterpret_cast<unsigned*>(&bq[qs][kb]);
#pragma unroll
            for (int i = 0; i < 4; ++i) u[i] ^= 0x80008000u;
        }

    float m[2][KP1];
#pragma unroll
    for (int qs = 0; qs < 2; ++qs)
#pragma unroll
        for (int j = 0; j < KP1; ++j) m[qs][j] = 1e30f;

#define INS(qs_, v_) do { \
    float d2_ = (v_); \
    _Pragma("unroll") \
    for (int j_ = KP1 - 1; j_ >= 1; --j_) \
        m[qs_][j_] = __builtin_amdgcn_fmed3f(d2_, m[qs_][j_ - 1], m[qs_][j_]); \
    m[qs_][0] = fminf(d2_, m[qs_][0]); \
} while (0)

    // stage 0.5*sq for the block's candidate range once (exact exponent shift)
    if (t < 128) {
        float4 v = reinterpret_cast<const float4*>(sqb + cstart)[t];
        v.x *= 0.5f; v.y *= 0.5f; v.z *= 0.5f; v.w *= 0.5f;
        reinterpret_cast<float4*>(sqs)[t] = v;
    }

    // staging: thread t owns 4 16B slots s = t + 256*i of the 1024-slot tile
    int gIdx[4], dIdx[4];
#pragma unroll
    for (int i = 0; i < 4; ++i) {
        int sl = t + 256 * i;
        int row = sl >> 4, col = sl & 15;
        gIdx[i] = row * DE + col * 8;                       // ushort units
        dIdx[i] = (row * 16 + (col ^ (row & 7))) * 8;
    }
    // A-frag base indices (row = q16 within a 16-cand subtile)
    int aIdx[4];
#pragma unroll
    for (int kb = 0; kb < 4; ++kb)
        aIdx[kb] = (q16 * 16 + ((kb * 4 + lg) ^ (q16 & 7))) * 8;

    short8 st[4];
#define STAGE_LOAD(tt_) do { \
    const ushort* sb_ = xs + (size_t)(cstart + (tt_) * TILE) * DE; \
    _Pragma("unroll") \
    for (int i_ = 0; i_ < 4; ++i_) \
        st[i_] = *reinterpret_cast<const short8*>(sb_ + gIdx[i_]); \
} while (0)
#define STAGE_WRITE(nb_) do { \
    _Pragma("unroll") \
    for (int i_ = 0; i_ < 4; ++i_) \
        *reinterpret_cast<short8*>(&lbuf[nb_][dIdx[i_]]) = st[i_]; \
} while (0)

    STAGE_LOAD(0);
    STAGE_WRITE(0);

    for (int tt = 0; tt < NTILE; ++tt) {
        __syncthreads();                     // publishes lbuf[tt&1] (and sqs on tt=0)
        if (tt + 1 < NTILE) STAGE_LOAD(tt + 1);
        const ushort* lb = lbuf[tt & 1];

        // ---- phase 1: ALL frag reads + ALL 32 MFMAs (8 independent chains)
        f32x4 acc[4][2];
#pragma unroll
        for (int cs = 0; cs < 4; ++cs) {
            short8 fa[4];
#pragma unroll
            for (int kb = 0; kb < 4; ++kb)
                fa[kb] = *reinterpret_cast<const short8*>(lb + cs * 2048 + aIdx[kb]);
            float4 sv = *reinterpret_cast<const float4*>(sqs + tt * TILE + cs * 16 + lg * 4);
#pragma unroll
            for (int qs = 0; qs < 2; ++qs) {
                acc[cs][qs] = {sv.x, sv.y, sv.z, sv.w};   // C-in = sq[c]/2; B = -x_q
#pragma unroll
                for (int kb = 0; kb < 4; ++kb)
                    acc[cs][qs] = __builtin_amdgcn_mfma_f32_16x16x32_bf16(
                        fa[kb], bq[qs][kb], acc[cs][qs], 0, 0, 0);
            }
        }
        // ---- phase 2: ALL inserts (352 VALU ops, covers the MFMA latency tails)
#pragma unroll
        for (int cs = 0; cs < 4; ++cs)
#pragma unroll
            for (int qs = 0; qs < 2; ++qs) {
                INS(qs, acc[cs][qs][0]);
                INS(qs, acc[cs][qs][1]);
                INS(qs, acc[cs][qs][2]);
                INS(qs, acc[cs][qs][3]);
            }

        if (tt + 1 < NTILE) STAGE_WRITE((tt + 1) & 1);  // buffer freed by this iter's sync
    }
#undef STAGE_LOAD
#undef STAGE_WRITE
#undef INS

    // ---- in-kernel lane-group merge, 2 phases (qs); block-contiguous part write
    float* mb = reinterpret_cast<float*>(lbuf);   // [4w][4lg][11][16] floats = 11264 B
    float* pout = part + (size_t)bid * PBLK;
#pragma unroll
    for (int qs = 0; qs < 2; ++qs) {
        __syncthreads();                     // lbuf free / previous phase done
#pragma unroll
        for (int j = 0; j < KP1; ++j)
            mb[((w * 4 + lg) * KP1 + j) * 16 + q16] = m[qs][j];
        __syncthreads();
        if (l < 16) {                        // lanes 0..15: q16 == l
            float mm[KP1];
#pragma unroll
            for (int j = 0; j < KP1; ++j)
                mm[j] = mb[((w * 4 + 0) * KP1 + j) * 16 + l];
#pragma unroll
            for (int g = 1; g < 4; ++g)
#pragma unroll
                for (int j = 0; j < KP1; ++j) {
                    float d2 = mb[((w * 4 + g) * KP1 + j) * 16 + l];
#pragma unroll
                    for (int jj = KP1 - 1; jj >= 1; --jj)
                        mm[jj] = __builtin_amdgcn_fmed3f(d2, mm[jj - 1], mm[jj]);
                    mm[0] = fminf(d2, mm[0]);
                }
#pragma unroll
            for (int j = 0; j < KP1; ++j)
                pout[((w * 2 + qs) * KP1 + j) * 16 + l] = mm[j];
        }
    }
}

// ---------------- Kernel 3: merge 16 partial lists (block-contiguous layout) -> sumk;
// dist^2 = 2*m + sqq (m holds sq[c]/2 - dot).
__global__ __launch_bounds__(256) void merge_kernel(
    const float* __restrict__ part, const float* __restrict__ sqb,
    float* __restrict__ sumk, float* __restrict__ psum)
{
    const int row = blockIdx.x * 256 + threadIdx.x;
    const int rid = row >> 7;                                  // 128 queries per knn block
    const int sub = ((row >> 5) & 3) * 2 + ((row >> 4) & 1);   // w*2+qs
    const int lane = row & 15;
    const float* pbase = part + (size_t)rid * 16 * PBLK + sub * (KP1 * 16) + lane;

    float m[KP1];
#pragma unroll
    for (int j = 0; j < KP1; ++j) m[j] = 1e30f;
#pragma unroll 4
    for (int ch = 0; ch < NCHUNK; ++ch) {
        const float* pc = pbase + ch * PBLK;
#pragma unroll
        for (int j = 0; j < KP1; ++j) {
            float d2 = pc[j * 16];
#pragma unroll
            for (int jj = KP1 - 1; jj >= 1; --jj)
                m[jj] = __builtin_amdgcn_fmed3f(d2, m[jj - 1], m[jj]);
            m[0] = fminf(d2, m[0]);
        }
    }
    const float sqq = sqb[row];
    float sum = 0.f;
#pragma unroll
    for (int j = 1; j < KP1; ++j)
        sum += sqrtf(fmaxf(fmaf(2.f, m[j], sqq), 1e-12f));
    sumk[row] = sum;

    float p = sum;
#pragma unroll
    for (int off = 32; off >= 1; off >>= 1) p += __shfl_xor(p, off, 64);
    __shared__ float red[4];
    if ((threadIdx.x & 63) == 0) red[threadIdx.x >> 6] = p;
    __syncthreads();
    if (threadIdx.x == 0) psum[blockIdx.x] = red[0] + red[1] + red[2] + red[3];
}

// ---------------- Kernel 4: mean over 32 partials -> q = EPS * mean^2
__global__ void reduce_kernel(const float* __restrict__ psum, float* __restrict__ qv)
{
    const int t = threadIdx.x;
    float p = (t < 32) ? psum[t] : 0.f;
#pragma unroll
    for (int off = 32; off >= 1; off >>= 1) p += __shfl_xor(p, off, 64);
    if (t == 0) {
        float mean = p * (1.0f / NN);
        qv[0] = EPSF * mean * mean;
    }
}

// ---------------- Kernel 5: out = q / (s^2 + q)
__global__ __launch_bounds__(256) void final_kernel(
    const float* __restrict__ sumk, const float* __restrict__ qv,
    float* __restrict__ out)
{
    const int i = blockIdx.x * 256 + threadIdx.x;
    const float qq = qv[0];
    const float sv = sumk[i];
    out[i] = qq / (fmaf(sv, sv, qq));
}

extern "C" void kernel_launch(void* const* d_in, const int* in_sizes, int n_in,
                              void* d_out, int out_size, void* d_ws, size_t ws_size,
                              hipStream_t stream)
{
    const float* s  = (const float*)d_in[0];
    const float* W1 = (const float*)d_in[1];
    const float* b1 = (const float*)d_in[2];
    const float* W2 = (const float*)d_in[3];
    const float* b2 = (const float*)d_in[4];
    float* out = (float*)d_out;

    char* ws = (char*)d_ws;
    __hip_bfloat16* xb = (__hip_bfloat16*)ws;                       // 2 MB
    float* sqb  = (float*)(ws + (size_t)NN * DE * 2);               // 32 KB
    float* part = sqb + NN;                                         // 1024*5632B = 5.77 MB
    float* sumk = part + (size_t)1024 * PBLK;                       // 32 KB
    float* psum = sumk + NN;                                        // 128 B
    float* qv   = psum + 32;                                        // 4 B
    ushort* W1h = (ushort*)(qv + 1);                                // 128 KB
    ushort* W1l = W1h + (size_t)HID * SD;                           // 128 KB
    ushort* W2h = W1l + (size_t)HID * SD;                           // 32 KB
    ushort* W2l = W2h + (size_t)DE * HID;                           // 32 KB

    wsplit_kernel<<<80, 256, 0, stream>>>(W1, W2, W1h, W1l, W2h, W2l);
    mlp_kernel<<<NN / 32, 256, 0, stream>>>(s, W1h, W1l, b1, W2h, W2l, b2, xb, sqb);
    knn_kernel<<<(NN / 128) * NSPLIT, 256, 0, stream>>>((const ushort*)xb, sqb, part);
    merge_kernel<<<NN / 256, 256, 0, stream>>>(part, sqb, sumk, psum);
    reduce_kernel<<<1, 64, 0, stream>>>(psum, qv);
    final_kernel<<<NN / 256, 256, 0, stream>>>(sumk, qv, out);
}

// Round 14
// 77.770 us; speedup vs baseline: 1.5022x; 1.0360x over previous
//
#include <hip/hip_runtime.h>
#include <hip/hip_bf16.h>

#define NN 8192
#define SD 512
#define HID 128
#define DE 128
#define KP1 11
#define EPSF 0.001f
#define NSPLIT 16
#define NCHUNK NSPLIT
#define TILE 64
#define NTILE ((NN / NSPLIT) / TILE)   // 8 tiles of 64 candidates per block
#define PBLK (4 * 2 * KP1 * 16)        // 1408 floats = 5632 B per block, contiguous

using short8 = __attribute__((ext_vector_type(8))) short;
using f32x4 = __attribute__((ext_vector_type(4))) float;

__device__ inline ushort f2bf(float f) {
    __hip_bfloat16 b = __float2bfloat16(f);
    return *reinterpret_cast<ushort*>(&b);
}
__device__ inline float bf2f(ushort u) {
    unsigned v = (unsigned)u << 16;
    union { unsigned u; float f; } c; c.u = v; return c.f;
}

// ---------------- Kernel 0: pre-split W1, W2 into hi/lo bf16
__global__ __launch_bounds__(256) void wsplit_kernel(
    const float* __restrict__ W1, const float* __restrict__ W2,
    ushort* __restrict__ W1h, ushort* __restrict__ W1l,
    ushort* __restrict__ W2h, ushort* __restrict__ W2l)
{
    const int bid = blockIdx.x;
    const float* src; ushort *dh, *dl; int base;
    if (bid < 64) { src = W1; dh = W1h; dl = W1l; base = bid * 1024; }
    else          { src = W2; dh = W2h; dl = W2l; base = (bid - 64) * 1024; }
    const int i = base + threadIdx.x * 4;
    float4 f = *reinterpret_cast<const float4*>(src + i);
    ushort h[4], lo[4];
    float fv[4] = {f.x, f.y, f.z, f.w};
#pragma unroll
    for (int j = 0; j < 4; ++j) {
        h[j] = f2bf(fv[j]);
        lo[j] = f2bf(fv[j] - bf2f(h[j]));
    }
    *reinterpret_cast<uint2*>(dh + i) = *reinterpret_cast<uint2*>(h);
    *reinterpret_cast<uint2*>(dl + i) = *reinterpret_cast<uint2*>(lo);
}

// ---------------- Kernel 1: split-bf16 MFMA MLP. Block = 32 rows x 128 cols, 4 waves.
__global__ __launch_bounds__(256) void mlp_kernel(
    const float* __restrict__ s, const ushort* __restrict__ W1h,
    const ushort* __restrict__ W1l, const float* __restrict__ b1,
    const ushort* __restrict__ W2h, const ushort* __restrict__ W2l,
    const float* __restrict__ b2, __hip_bfloat16* __restrict__ xb,
    float* __restrict__ sqb)
{
    __shared__ __align__(16) ushort sbh[2][32 * 32];
    __shared__ __align__(16) ushort sbl[2][32 * 32];
    __shared__ __align__(16) ushort hbh[32 * 128];
    __shared__ __align__(16) ushort hbl[32 * 128];
    __shared__ __align__(16) ushort xtile[32 * 128];
    __shared__ float sqpart[4 * 32];

    const int t = threadIdx.x;
    const int w = t >> 6, l = t & 63;
    const int lc = l & 15, c4 = l >> 4;
    const int rb = blockIdx.x * 32;
    const int cb = w * 32;

    const int srow = t >> 3, skq = t & 7;
    const int ssl = ((skq >> 1) + (srow >> 2)) & 3;
    const int sByte = srow * 64 + (ssl ^ (srow & 3)) * 16 + (skq & 1) * 8;
    const float* sgbase = s + (size_t)(rb + srow) * SD + skq * 4;

    float4 sf;
#define STAGE_LOAD_S(kt_) sf = *reinterpret_cast<const float4*>(sgbase + (kt_) * 32)
#define STAGE_WRITE_S(b_) do { \
    float fv_[4] = {sf.x, sf.y, sf.z, sf.w}; \
    ushort h_[4], lo_[4]; \
    _Pragma("unroll") \
    for (int j_ = 0; j_ < 4; ++j_) { \
        h_[j_] = f2bf(fv_[j_]); \
        lo_[j_] = f2bf(fv_[j_] - bf2f(h_[j_])); \
    } \
    *reinterpret_cast<uint2*>(reinterpret_cast<char*>(sbh[b_]) + sByte) = *reinterpret_cast<uint2*>(h_); \
    *reinterpret_cast<uint2*>(reinterpret_cast<char*>(sbl[b_]) + sByte) = *reinterpret_cast<uint2*>(lo_); \
} while (0)

    int aByte[2];
#pragma unroll
    for (int rt = 0; rt < 2; ++rt) {
        int row = rt * 16 + lc;
        int sl = ((c4 + (row >> 2)) & 3) ^ (row & 3);
        aByte[rt] = row * 64 + sl * 16;
    }

    const ushort* w1hp[2]; const ushort* w1lp[2];
#pragma unroll
    for (int ct = 0; ct < 2; ++ct) {
        int col = cb + ct * 16 + lc;
        w1hp[ct] = W1h + (size_t)col * SD + c4 * 8;
        w1lp[ct] = W1l + (size_t)col * SD + c4 * 8;
    }

    f32x4 acc1[2][2];
#pragma unroll
    for (int rt = 0; rt < 2; ++rt)
#pragma unroll
        for (int ct = 0; ct < 2; ++ct) acc1[rt][ct] = {0.f, 0.f, 0.f, 0.f};

    STAGE_LOAD_S(0);
    STAGE_WRITE_S(0);
    short8 bh[2], bl[2], nbh[2], nbl[2];
#pragma unroll
    for (int ct = 0; ct < 2; ++ct) {
        bh[ct] = *reinterpret_cast<const short8*>(w1hp[ct]);
        bl[ct] = *reinterpret_cast<const short8*>(w1lp[ct]);
    }

    for (int kt = 0; kt < 16; ++kt) {
        __syncthreads();
        if (kt < 15) STAGE_LOAD_S(kt + 1);
        short8 ah[2], al[2];
#pragma unroll
        for (int rt = 0; rt < 2; ++rt) {
            ah[rt] = *reinterpret_cast<const short8*>(
                reinterpret_cast<char*>(sbh[kt & 1]) + aByte[rt]);
            al[rt] = *reinterpret_cast<const short8*>(
                reinterpret_cast<char*>(sbl[kt & 1]) + aByte[rt]);
        }
        if (kt < 15) {
#pragma unroll
            for (int ct = 0; ct < 2; ++ct) {
                nbh[ct] = *reinterpret_cast<const short8*>(w1hp[ct] + (kt + 1) * 32);
                nbl[ct] = *reinterpret_cast<const short8*>(w1lp[ct] + (kt + 1) * 32);
            }
        }
#pragma unroll
        for (int rt = 0; rt < 2; ++rt)
#pragma unroll
            for (int ct = 0; ct < 2; ++ct) {
                acc1[rt][ct] = __builtin_amdgcn_mfma_f32_16x16x32_bf16(ah[rt], bh[ct], acc1[rt][ct], 0, 0, 0);
                acc1[rt][ct] = __builtin_amdgcn_mfma_f32_16x16x32_bf16(ah[rt], bl[ct], acc1[rt][ct], 0, 0, 0);
                acc1[rt][ct] = __builtin_amdgcn_mfma_f32_16x16x32_bf16(al[rt], bh[ct], acc1[rt][ct], 0, 0, 0);
            }
        if (kt < 15) {
            STAGE_WRITE_S((kt + 1) & 1);
#pragma unroll
            for (int ct = 0; ct < 2; ++ct) { bh[ct] = nbh[ct]; bl[ct] = nbl[ct]; }
        }
    }

    float b1v[2];
#pragma unroll
    for (int ct = 0; ct < 2; ++ct) b1v[ct] = b1[cb + ct * 16 + lc];
#pragma unroll
    for (int rt = 0; rt < 2; ++rt)
#pragma unroll
        for (int ct = 0; ct < 2; ++ct)
#pragma unroll
            for (int reg = 0; reg < 4; ++reg) {
                float v = fmaxf(acc1[rt][ct][reg] + b1v[ct], 0.f);
                ushort hh = f2bf(v);
                ushort hl = f2bf(v - bf2f(hh));
                int row = rt * 16 + c4 * 4 + reg;
                int kcol = cb + ct * 16 + lc;
                int sl = (kcol >> 3) ^ (row & 15);
                int byte = row * 256 + sl * 16 + (kcol & 7) * 2;
                *reinterpret_cast<ushort*>(reinterpret_cast<char*>(hbh) + byte) = hh;
                *reinterpret_cast<ushort*>(reinterpret_cast<char*>(hbl) + byte) = hl;
            }
    __syncthreads();

    f32x4 acc2[2][2];
#pragma unroll
    for (int rt = 0; rt < 2; ++rt)
#pragma unroll
        for (int ct = 0; ct < 2; ++ct) acc2[rt][ct] = {0.f, 0.f, 0.f, 0.f};

#pragma unroll
    for (int kt = 0; kt < 4; ++kt) {
        short8 ah[2], al[2];
#pragma unroll
        for (int rt = 0; rt < 2; ++rt) {
            int row = rt * 16 + lc;
            int sl = (kt * 4 + c4) ^ (row & 15);
            int byte = row * 256 + sl * 16;
            ah[rt] = *reinterpret_cast<const short8*>(reinterpret_cast<char*>(hbh) + byte);
            al[rt] = *reinterpret_cast<const short8*>(reinterpret_cast<char*>(hbl) + byte);
        }
        short8 wh[2], wl[2];
#pragma unroll
        for (int ct = 0; ct < 2; ++ct) {
            int col = cb + ct * 16 + lc;
            wh[ct] = *reinterpret_cast<const short8*>(W2h + (size_t)col * HID + kt * 32 + c4 * 8);
            wl[ct] = *reinterpret_cast<const short8*>(W2l + (size_t)col * HID + kt * 32 + c4 * 8);
        }
#pragma unroll
        for (int rt = 0; rt < 2; ++rt)
#pragma unroll
            for (int ct = 0; ct < 2; ++ct) {
                acc2[rt][ct] = __builtin_amdgcn_mfma_f32_16x16x32_bf16(ah[rt], wh[ct], acc2[rt][ct], 0, 0, 0);
                acc2[rt][ct] = __builtin_amdgcn_mfma_f32_16x16x32_bf16(ah[rt], wl[ct], acc2[rt][ct], 0, 0, 0);
                acc2[rt][ct] = __builtin_amdgcn_mfma_f32_16x16x32_bf16(al[rt], wh[ct], acc2[rt][ct], 0, 0, 0);
            }
    }

    float b2v[2];
#pragma unroll
    for (int ct = 0; ct < 2; ++ct) b2v[ct] = b2[cb + ct * 16 + lc];
    float p[8];
#pragma unroll
    for (int j = 0; j < 8; ++j) p[j] = 0.f;
#pragma unroll
    for (int rt = 0; rt < 2; ++rt)
#pragma unroll
        for (int ct = 0; ct < 2; ++ct)
#pragma unroll
            for (int reg = 0; reg < 4; ++reg) {
                float v = acc2[rt][ct][reg] + b2v[ct];
                ushort xv = f2bf(v);
                float xf = bf2f(xv);
                p[rt * 4 + reg] = fmaf(xf, xf, p[rt * 4 + reg]);
                int row = rt * 16 + c4 * 4 + reg;
                int e = cb + ct * 16 + lc;
                xtile[row * 128 + e] = xv;
            }
#pragma unroll
    for (int j = 0; j < 8; ++j) {
#pragma unroll
        for (int off = 8; off >= 1; off >>= 1) p[j] += __shfl_xor(p[j], off, 16);
    }
    if (lc == 0) {
#pragma unroll
        for (int rt = 0; rt < 2; ++rt)
#pragma unroll
            for (int reg = 0; reg < 4; ++reg)
                sqpart[w * 32 + rt * 16 + c4 * 4 + reg] = p[rt * 4 + reg];
    }
    __syncthreads();
    if (t < 32)
        sqb[rb + t] = sqpart[t] + sqpart[32 + t] + sqpart[64 + t] + sqpart[96 + t];
    const short8* xsv = reinterpret_cast<const short8*>(xtile);
    short8* xg = reinterpret_cast<short8*>(reinterpret_cast<ushort*>(xb) + (size_t)rb * DE);
    xg[t] = xsv[t];
    xg[t + 256] = xsv[t + 256];
}

// ---------------- Kernel 2: per-row top-11 of d2'' = sq[c]/2 - x_q.x_c.
// r5-proven loop shape + C-in=sq/2 + negated queries. NEW: per-block tile-loop
// PHASE STAGGER (start tile = (bid*5)&7, candidates wrap) so co-resident blocks
// mix LDS-heavy and VALU-heavy phases instead of colliding in lockstep.
__global__ __launch_bounds__(256) void knn_kernel(
    const ushort* __restrict__ xs, const float* __restrict__ sqb,
    float* __restrict__ part)
{
    __shared__ __align__(16) ushort lbuf[2][TILE * DE];   // 2 x 16KB (merge overlays)
    __shared__ __align__(16) float sqs[NN / NSPLIT];      // 2KB

    const int bid = blockIdx.x;              // 1024 = 64 row-groups x 16 cand-splits
    const int rid = bid >> 4, cid = bid & 15;
    const int t = threadIdx.x;
    const int w = t >> 6, l = t & 63;
    const int q16 = l & 15, lg = l >> 4;
    const int kk = lg * 8;
    const int qb = rid * 128 + w * 32;
    const int cstart = cid * (NN / NSPLIT);  // 512 candidates per block
    const int ph = (bid * 5) & (NTILE - 1);  // phase stagger

    // B-frags: NEGATED queries (sign-bit XOR on packed bf16 pairs; exact)
    short8 bq[2][4];
#pragma unroll
    for (int qs = 0; qs < 2; ++qs)
#pragma unroll
        for (int kb = 0; kb < 4; ++kb) {
            bq[qs][kb] = *reinterpret_cast<const short8*>(
                xs + (size_t)(qb + qs * 16 + q16) * DE + kb * 32 + kk);
            unsigned* u = reinterpret_cast<unsigned*>(&bq[qs][kb]);
#pragma unroll
            for (int i = 0; i < 4; ++i) u[i] ^= 0x80008000u;
        }

    float m[2][KP1];
#pragma unroll
    for (int qs = 0; qs < 2; ++qs)
#pragma unroll
        for (int j = 0; j < KP1; ++j) m[qs][j] = 1e30f;

#define INS(qs_, v_) do { \
    float d2_ = (v_); \
    _Pragma("unroll") \
    for (int j_ = KP1 - 1; j_ >= 1; --j_) \
        m[qs_][j_] = __builtin_amdgcn_fmed3f(d2_, m[qs_][j_ - 1], m[qs_][j_]); \
    m[qs_][0] = fminf(d2_, m[qs_][0]); \
} while (0)

    // stage 0.5*sq for the block's candidate range once (exact exponent shift)
    if (t < 128) {
        float4 v = reinterpret_cast<const float4*>(sqb + cstart)[t];
        v.x *= 0.5f; v.y *= 0.5f; v.z *= 0.5f; v.w *= 0.5f;
        reinterpret_cast<float4*>(sqs)[t] = v;
    }

    // staging: thread t owns 4 16B slots s = t + 256*i of the 1024-slot tile
    int gIdx[4], dIdx[4];
#pragma unroll
    for (int i = 0; i < 4; ++i) {
        int sl = t + 256 * i;
        int row = sl >> 4, col = sl & 15;
        gIdx[i] = row * DE + col * 8;                       // ushort units
        dIdx[i] = (row * 16 + (col ^ (row & 7))) * 8;
    }
    // A-frag base indices (row = q16 within a 16-cand subtile)
    int aIdx[4];
#pragma unroll
    for (int kb = 0; kb < 4; ++kb)
        aIdx[kb] = (q16 * 16 + ((kb * 4 + lg) ^ (q16 & 7))) * 8;

    short8 st[4];
#define STAGE_LOAD(tc_) do { \
    const ushort* sb_ = xs + (size_t)(cstart + (tc_) * TILE) * DE; \
    _Pragma("unroll") \
    for (int i_ = 0; i_ < 4; ++i_) \
        st[i_] = *reinterpret_cast<const short8*>(sb_ + gIdx[i_]); \
} while (0)
#define STAGE_WRITE(nb_) do { \
    _Pragma("unroll") \
    for (int i_ = 0; i_ < 4; ++i_) \
        *reinterpret_cast<short8*>(&lbuf[nb_][dIdx[i_]]) = st[i_]; \
} while (0)

    STAGE_LOAD(ph);
    STAGE_WRITE(0);

    for (int tt = 0; tt < NTILE; ++tt) {
        __syncthreads();                     // publishes lbuf[tt&1] (and sqs on tt=0)
        const int tc = (tt + ph) & (NTILE - 1);
        if (tt + 1 < NTILE) STAGE_LOAD((tt + 1 + ph) & (NTILE - 1));
        const ushort* lb = lbuf[tt & 1];
#pragma unroll
        for (int cs = 0; cs < 4; ++cs) {     // 16-cand subtiles
            short8 fa[4];
#pragma unroll
            for (int kb = 0; kb < 4; ++kb)
                fa[kb] = *reinterpret_cast<const short8*>(lb + cs * 2048 + aIdx[kb]);
            float4 sv = *reinterpret_cast<const float4*>(sqs + tc * TILE + cs * 16 + lg * 4);
#pragma unroll
            for (int qs = 0; qs < 2; ++qs) {
                f32x4 acc = {sv.x, sv.y, sv.z, sv.w};   // C-in = sq[c]/2; B = -x_q
#pragma unroll
                for (int kb = 0; kb < 4; ++kb)
                    acc = __builtin_amdgcn_mfma_f32_16x16x32_bf16(fa[kb], bq[qs][kb], acc, 0, 0, 0);
                INS(qs, acc[0]);
                INS(qs, acc[1]);
                INS(qs, acc[2]);
                INS(qs, acc[3]);
            }
        }
        if (tt + 1 < NTILE) STAGE_WRITE((tt + 1) & 1);  // buffer freed by this iter's sync
    }
#undef STAGE_LOAD
#undef STAGE_WRITE
#undef INS

    // ---- in-kernel lane-group merge, 2 phases (qs); block-contiguous part write
    float* mb = reinterpret_cast<float*>(lbuf);   // [4w][4lg][11][16] floats = 11264 B
    float* pout = part + (size_t)bid * PBLK;
#pragma unroll
    for (int qs = 0; qs < 2; ++qs) {
        __syncthreads();                     // lbuf free / previous phase done
#pragma unroll
        for (int j = 0; j < KP1; ++j)
            mb[((w * 4 + lg) * KP1 + j) * 16 + q16] = m[qs][j];
        __syncthreads();
        if (l < 16) {                        // lanes 0..15: q16 == l
            float mm[KP1];
#pragma unroll
            for (int j = 0; j < KP1; ++j)
                mm[j] = mb[((w * 4 + 0) * KP1 + j) * 16 + l];
#pragma unroll
            for (int g = 1; g < 4; ++g)
#pragma unroll
                for (int j = 0; j < KP1; ++j) {
                    float d2 = mb[((w * 4 + g) * KP1 + j) * 16 + l];
#pragma unroll
                    for (int jj = KP1 - 1; jj >= 1; --jj)
                        mm[jj] = __builtin_amdgcn_fmed3f(d2, mm[jj - 1], mm[jj]);
                    mm[0] = fminf(d2, mm[0]);
                }
#pragma unroll
            for (int j = 0; j < KP1; ++j)
                pout[((w * 2 + qs) * KP1 + j) * 16 + l] = mm[j];
        }
    }
}

// ---------------- Kernel 3: merge 16 partial lists (block-contiguous layout) -> sumk;
// dist^2 = 2*m + sqq. Also emits per-block partial sums.
__global__ __launch_bounds__(256) void merge_kernel(
    const float* __restrict__ part, const float* __restrict__ sqb,
    float* __restrict__ sumk, float* __restrict__ psum)
{
    const int row = blockIdx.x * 256 + threadIdx.x;
    const int rid = row >> 7;                                  // 128 queries per knn block
    const int sub = ((row >> 5) & 3) * 2 + ((row >> 4) & 1);   // w*2+qs
    const int lane = row & 15;
    const float* pbase = part + (size_t)rid * 16 * PBLK + sub * (KP1 * 16) + lane;

    float m[KP1];
#pragma unroll
    for (int j = 0; j < KP1; ++j) m[j] = 1e30f;
#pragma unroll 4
    for (int ch = 0; ch < NCHUNK; ++ch) {
        const float* pc = pbase + ch * PBLK;
#pragma unroll
        for (int j = 0; j < KP1; ++j) {
            float d2 = pc[j * 16];
#pragma unroll
            for (int jj = KP1 - 1; jj >= 1; --jj)
                m[jj] = __builtin_amdgcn_fmed3f(d2, m[jj - 1], m[jj]);
            m[0] = fminf(d2, m[0]);
        }
    }
    const float sqq = sqb[row];
    float sum = 0.f;
#pragma unroll
    for (int j = 1; j < KP1; ++j)
        sum += sqrtf(fmaxf(fmaf(2.f, m[j], sqq), 1e-12f));
    sumk[row] = sum;

    float p = sum;
#pragma unroll
    for (int off = 32; off >= 1; off >>= 1) p += __shfl_xor(p, off, 64);
    __shared__ float red[4];
    if ((threadIdx.x & 63) == 0) red[threadIdx.x >> 6] = p;
    __syncthreads();
    if (threadIdx.x == 0) psum[blockIdx.x] = red[0] + red[1] + red[2] + red[3];
}

// ---------------- Kernel 4: final (reduce folded in): qv from psum[32], then
// out = q / (s^2 + q)
__global__ __launch_bounds__(256) void final_kernel(
    const float* __restrict__ sumk, const float* __restrict__ psum,
    float* __restrict__ out)
{
    __shared__ float qsh;
    const int t = threadIdx.x;
    if (t < 64) {
        float p = (t < 32) ? psum[t] : 0.f;
#pragma unroll
        for (int off = 32; off >= 1; off >>= 1) p += __shfl_xor(p, off, 64);
        if (t == 0) {
            float mean = p * (1.0f / NN);
            qsh = EPSF * mean * mean;
        }
    }
    __syncthreads();
    const float qq = qsh;
    const int i = blockIdx.x * 256 + t;
    const float sv = sumk[i];
    out[i] = qq / (fmaf(sv, sv, qq));
}

extern "C" void kernel_launch(void* const* d_in, const int* in_sizes, int n_in,
                              void* d_out, int out_size, void* d_ws, size_t ws_size,
                              hipStream_t stream)
{
    const float* s  = (const float*)d_in[0];
    const float* W1 = (const float*)d_in[1];
    const float* b1 = (const float*)d_in[2];
    const float* W2 = (const float*)d_in[3];
    const float* b2 = (const float*)d_in[4];
    float* out = (float*)d_out;

    char* ws = (char*)d_ws;
    __hip_bfloat16* xb = (__hip_bfloat16*)ws;                       // 2 MB
    float* sqb  = (float*)(ws + (size_t)NN * DE * 2);               // 32 KB
    float* part = sqb + NN;                                         // 1024*5632B = 5.77 MB
    float* sumk = part + (size_t)1024 * PBLK;                       // 32 KB
    float* psum = sumk + NN;                                        // 128 B
    ushort* W1h = (ushort*)(psum + 32);                             // 128 KB
    ushort* W1l = W1h + (size_t)HID * SD;                           // 128 KB
    ushort* W2h = W1l + (size_t)HID * SD;                           // 32 KB
    ushort* W2l = W2h + (size_t)DE * HID;                           // 32 KB

    wsplit_kernel<<<80, 256, 0, stream>>>(W1, W2, W1h, W1l, W2h, W2l);
    mlp_kernel<<<NN / 32, 256, 0, stream>>>(s, W1h, W1l, b1, W2h, W2l, b2, xb, sqb);
    knn_kernel<<<(NN / 128) * NSPLIT, 256, 0, stream>>>((const ushort*)xb, sqb, part);
    merge_kernel<<<NN / 256, 256, 0, stream>>>(part, sqb, sumk, psum);
    final_kernel<<<NN / 256, 256, 0, stream>>>(sumk, psum, out);
}